// Round 1
// baseline (713.546 us; speedup 1.0000x reference)
//
#include <hip/hip_runtime.h>
#include <hip/hip_bf16.h>
#include <stdint.h>

// Problem constants (fixed by reference setup_inputs)
#define PB 8          // batch
#define PN 16384      // points
#define PC 64         // channels (Cin == Cout == 64)
#define PR 32         // voxel resolution
#define PR3 32768     // R^3
#define PRP 34        // padded resolution

typedef __attribute__((ext_vector_type(8))) short bf16x8;
typedef __attribute__((ext_vector_type(16))) float f32x16;

__device__ __forceinline__ unsigned short f2bf(float f) {
  union { float f; unsigned u; } v; v.f = f;
  unsigned r = v.u + 0x7FFFu + ((v.u >> 16) & 1u);
  return (unsigned short)(r >> 16);
}

// ---------------------------------------------------------------------------
// 1) per-batch coord stats: mean(3) and scale = 2*max||c-mean||
// ---------------------------------------------------------------------------
__global__ void coord_stats_kernel(const float* __restrict__ coords, float* __restrict__ ms) {
  int b = blockIdx.x, t = threadIdx.x;
  __shared__ float wsum[4][3];
  __shared__ float wmax[4];
  __shared__ float meanv[3];
  const float* c0 = coords + (size_t)b * 3 * PN;
  float s0 = 0.f, s1 = 0.f, s2 = 0.f;
  for (int n = t; n < PN; n += 256) {
    s0 += c0[n]; s1 += c0[PN + n]; s2 += c0[2 * PN + n];
  }
  for (int off = 32; off > 0; off >>= 1) {
    s0 += __shfl_down(s0, off); s1 += __shfl_down(s1, off); s2 += __shfl_down(s2, off);
  }
  if ((t & 63) == 0) { wsum[t >> 6][0] = s0; wsum[t >> 6][1] = s1; wsum[t >> 6][2] = s2; }
  __syncthreads();
  if (t == 0) {
    for (int d = 0; d < 3; ++d)
      meanv[d] = (wsum[0][d] + wsum[1][d] + wsum[2][d] + wsum[3][d]) * (1.0f / PN);
  }
  __syncthreads();
  float m0 = meanv[0], m1 = meanv[1], m2 = meanv[2];
  float mx = 0.f;
  for (int n = t; n < PN; n += 256) {
    float dx = c0[n] - m0, dy = c0[PN + n] - m1, dz = c0[2 * PN + n] - m2;
    mx = fmaxf(mx, dx * dx + dy * dy + dz * dz);
  }
  for (int off = 32; off > 0; off >>= 1) mx = fmaxf(mx, __shfl_down(mx, off));
  if ((t & 63) == 0) wmax[t >> 6] = mx;
  __syncthreads();
  if (t == 0) {
    float m = fmaxf(fmaxf(wmax[0], wmax[1]), fmaxf(wmax[2], wmax[3]));
    ms[b * 4 + 0] = meanv[0]; ms[b * 4 + 1] = meanv[1]; ms[b * 4 + 2] = meanv[2];
    ms[b * 4 + 3] = 2.0f * sqrtf(m);
  }
}

// ---------------------------------------------------------------------------
// 2) normalized coords + rounded flat voxel index
// ---------------------------------------------------------------------------
__global__ void nc_vox_kernel(const float* __restrict__ coords, const float* __restrict__ ms,
                              float* __restrict__ nc, int* __restrict__ vflat) {
  int i = blockIdx.x * 256 + threadIdx.x;
  if (i >= PB * PN) return;
  int b = i >> 14, n = i & (PN - 1);
  float sc = ms[b * 4 + 3];
  int vi[3];
  #pragma unroll
  for (int d = 0; d < 3; ++d) {
    float c = coords[((size_t)b * 3 + d) * PN + n];
    float q = (c - ms[b * 4 + d]) / sc + 0.5f;
    float v = fminf(fmaxf(q * 32.0f, 0.0f), 31.0f);
    nc[((size_t)b * 3 + d) * PN + n] = v;
    vi[d] = (int)rintf(v);  // round half to even, matches jnp.round
  }
  vflat[i] = (vi[0] * PR + vi[1]) * PR + vi[2];
}

// ---------------------------------------------------------------------------
// 3) scatter-add features into (B, R3, C) sums + counts. LDS transpose so the
//    64 atomic lanes cover 64 consecutive channels (256B bursts).
// ---------------------------------------------------------------------------
__global__ void scatter_kernel(const float* __restrict__ feats, const int* __restrict__ vflat,
                               float* __restrict__ sums, float* __restrict__ cnts) {
  int b = blockIdx.y, p0 = blockIdx.x * 64, t = threadIdx.x;
  __shared__ float fl[64 * 65];
  for (int k = 0; k < 16; ++k) {
    int i = t + k * 256;
    int c = i >> 6, p = i & 63;
    fl[c * 65 + p] = feats[((size_t)b * PC + c) * PN + p0 + p];
  }
  __syncthreads();
  if (t < 64) atomicAdd(&cnts[b * PR3 + vflat[b * PN + p0 + t]], 1.0f);
  int cc = t & 63, pp = t >> 6;
  for (int i = 0; i < 16; ++i) {
    int p = pp * 16 + i;
    int v = vflat[b * PN + p0 + p];
    atomicAdd(&sums[((size_t)b * PR3 + v) * PC + cc], fl[cc * 65 + p]);
  }
}

// ---------------------------------------------------------------------------
// 4) finalize: avg = sums/max(cnt,1) -> bf16 into padded grid (B,34,34,34,64)
// ---------------------------------------------------------------------------
__global__ void finalize_kernel(const float* __restrict__ sums, const float* __restrict__ cnts,
                                unsigned short* __restrict__ g0) {
  int idx = blockIdx.x * 256 + threadIdx.x;   // over B*R3*8 chunks
  int co = idx & 7, v = (idx >> 3) & (PR3 - 1), b = idx >> 18;
  float cnt = cnts[b * PR3 + v];
  float inv = 1.0f / fmaxf(cnt, 1.0f);
  const float4* sp = (const float4*)(sums + ((size_t)(b * PR3 + v) * PC) + co * 8);
  float4 A = sp[0], B4 = sp[1];
  float vals[8] = {A.x, A.y, A.z, A.w, B4.x, B4.y, B4.z, B4.w};
  unsigned short h[8];
  #pragma unroll
  for (int k = 0; k < 8; ++k) h[k] = f2bf(vals[k] * inv);
  int z = v >> 10, y = (v >> 5) & 31, x = v & 31;
  size_t o = ((((size_t)b * PRP + (z + 1)) * PRP + (y + 1)) * PRP + (x + 1)) * PC + co * 8;
  uint4 pk;
  pk.x = h[0] | ((unsigned)h[1] << 16); pk.y = h[2] | ((unsigned)h[3] << 16);
  pk.z = h[4] | ((unsigned)h[5] << 16); pk.w = h[6] | ((unsigned)h[7] << 16);
  *(uint4*)(g0 + o) = pk;
}

// ---------------------------------------------------------------------------
// 5) weight transposes: conv w(O,I,3,3,3) -> bf16 [tap][o][i]; pf w(O,I) -> [i][o]
// ---------------------------------------------------------------------------
__global__ void tconv_kernel(const float* __restrict__ w, unsigned short* __restrict__ wkt) {
  int idx = blockIdx.x * 256 + threadIdx.x;
  if (idx >= 27 * 64 * 64) return;
  int i = idx & 63, o = (idx >> 6) & 63, tap = idx >> 12;
  wkt[idx] = f2bf(w[(o * 64 + i) * 27 + tap]);
}
__global__ void tpf_kernel(const float* __restrict__ pw, float* __restrict__ wt) {
  int idx = blockIdx.x * 256 + threadIdx.x;
  if (idx >= 4096) return;
  int o = idx & 63, ci = idx >> 6;
  wt[ci * 64 + o] = pw[o * 64 + ci];
}

// ---------------------------------------------------------------------------
// 6) 3x3x3 conv, 64->64 ch, bf16 MFMA 32x32x16 implicit GEMM.
//    Block: 8x8x8 output voxels x 64 couts, 4 waves (each 128 vox x 64 co).
//    LDS: 10x10x10x64 bf16 input tile (XOR-swizzled 16B chunks) + 2x8KB weight dbuf.
//    Also accumulates GroupNorm sum/sumsq per (b, group) via atomics.
// ---------------------------------------------------------------------------
__global__ __launch_bounds__(256, 1) void conv3_kernel(
    const unsigned short* __restrict__ gin, const unsigned short* __restrict__ wkt,
    const float* __restrict__ bias, float* __restrict__ outp, float* __restrict__ stats) {
  extern __shared__ char smem[];  // [0,128000) input, [128000,144384) weights dbuf
  const int t = threadIdx.x;
  const int tile = blockIdx.x, b = blockIdx.y;
  const int tz = tile >> 4, ty = (tile >> 2) & 3, tx = tile & 3;
  const int z0 = tz * 8, y0 = ty * 8, x0 = tx * 8;

  // stage input tile (1000 voxels x 128B = 8000 16B chunks)
  {
    const size_t gbase = (size_t)b * (PRP * PRP * PRP * PC);
    for (int it = 0; it < 32; ++it) {
      int q = t + it * 256;
      if (q < 8000) {
        int vl = q >> 3, cc = q & 7;
        int zz = vl / 100, rem = vl - zz * 100;
        int yy = rem / 10, xx = rem - yy * 10;
        size_t go = gbase + (((size_t)(z0 + zz) * PRP + (y0 + yy)) * PRP + (x0 + xx)) * PC + cc * 8;
        uint4 d = *(const uint4*)(gin + go);
        *(uint4*)(smem + (vl * 128 + ((cc ^ (vl & 7)) << 4))) = d;
      }
    }
  }
  // stage weights for tap 0 into buffer 0
  {
    #pragma unroll
    for (int u = 0; u < 2; ++u) {
      int q = t * 2 + u;
      int o = q >> 3, cc = q & 7;
      uint4 d = ((const uint4*)wkt)[q];
      *(uint4*)(smem + 128000 + (o * 128 + ((cc ^ (o & 7)) << 4))) = d;
    }
  }
  __syncthreads();

  const int wv = t >> 6, l31 = t & 31, hi = (t >> 5) & 1;
  int vbase[4];
  #pragma unroll
  for (int m = 0; m < 4; ++m) {
    int vi = wv * 128 + m * 32 + l31;
    int z = vi >> 6, y = (vi >> 3) & 7, x = vi & 7;
    vbase[m] = z * 100 + y * 10 + x;
  }

  f32x16 acc[4][2];
  #pragma unroll
  for (int m = 0; m < 4; ++m)
    #pragma unroll
    for (int nb = 0; nb < 2; ++nb)
      #pragma unroll
      for (int r = 0; r < 16; ++r) acc[m][nb][r] = 0.0f;

  for (int tap = 0; tap < 27; ++tap) {
    if (tap + 1 < 27) {  // prefetch next tap's weights into other buffer
      char* wb = smem + 128000 + (((tap + 1) & 1) * 8192);
      #pragma unroll
      for (int u = 0; u < 2; ++u) {
        int q = t * 2 + u;
        int o = q >> 3, cc = q & 7;
        uint4 d = ((const uint4*)wkt)[(tap + 1) * 512 + q];
        *(uint4*)(wb + (o * 128 + ((cc ^ (o & 7)) << 4))) = d;
      }
    }
    const char* wb = smem + 128000 + ((tap & 1) * 8192);
    int dz = tap / 9, r9 = tap - dz * 9;
    int dy = r9 / 3, dx = r9 - dy * 3;
    int toff = dz * 100 + dy * 10 + dx;
    #pragma unroll
    for (int kk = 0; kk < 4; ++kk) {
      bf16x8 afr[4], bfr[2];
      #pragma unroll
      for (int m = 0; m < 4; ++m) {
        int vl = vbase[m] + toff;
        afr[m] = *(const bf16x8*)(smem + (vl * 128 + (((kk * 2 + hi) ^ (vl & 7)) << 4)));
      }
      #pragma unroll
      for (int nb = 0; nb < 2; ++nb) {
        int o = nb * 32 + l31;
        bfr[nb] = *(const bf16x8*)(wb + (o * 128 + (((kk * 2 + hi) ^ (o & 7)) << 4)));
      }
      #pragma unroll
      for (int m = 0; m < 4; ++m)
        #pragma unroll
        for (int nb = 0; nb < 2; ++nb)
          acc[m][nb] = __builtin_amdgcn_mfma_f32_32x32x16_bf16(afr[m], bfr[nb], acc[m][nb], 0, 0, 0);
    }
    __syncthreads();
  }

  // epilogue: +bias, store raw fp32 (B,R3,C), accumulate GN partials
  float sg[2] = {0.f, 0.f}, ssg[2] = {0.f, 0.f};
  #pragma unroll
  for (int nb = 0; nb < 2; ++nb) {
    int cn = nb * 32 + l31;
    float bv = bias[cn];
    #pragma unroll
    for (int m = 0; m < 4; ++m) {
      #pragma unroll
      for (int r = 0; r < 16; ++r) {
        int row = (r & 3) + 8 * (r >> 2) + 4 * hi;
        int vi = wv * 128 + m * 32 + row;
        int Z = z0 + (vi >> 6), Y = y0 + ((vi >> 3) & 7), X = x0 + (vi & 7);
        int vg = (Z * PR + Y) * PR + X;
        float val = acc[m][nb][r] + bv;
        outp[((size_t)b * PR3 + vg) * PC + cn] = val;
        sg[nb] += val; ssg[nb] += val * val;
      }
    }
  }
  #pragma unroll
  for (int nb = 0; nb < 2; ++nb) {
    sg[nb] += __shfl_down(sg[nb], 32);
    ssg[nb] += __shfl_down(ssg[nb], 32);
    #pragma unroll
    for (int off = 1; off <= 4; off <<= 1) {
      sg[nb] += __shfl_xor(sg[nb], off);
      ssg[nb] += __shfl_xor(ssg[nb], off);
    }
  }
  if (hi == 0 && (l31 & 7) == 0) {
    #pragma unroll
    for (int nb = 0; nb < 2; ++nb) {
      int g = (nb * 32 + l31) >> 3;
      atomicAdd(&stats[((size_t)b * 8 + g) * 2 + 0], sg[nb]);
      atomicAdd(&stats[((size_t)b * 8 + g) * 2 + 1], ssg[nb]);
    }
  }
}

// ---------------------------------------------------------------------------
// 7) GN (+Swish) from raw fp32 -> bf16 padded grid      (after conv1)
//    GN (no swish) in-place fp32                        (after conv2)
// ---------------------------------------------------------------------------
__global__ void gn_swish_bf16_kernel(const float* __restrict__ raw, const float* __restrict__ st,
                                     const float* __restrict__ gw, const float* __restrict__ gb,
                                     unsigned short* __restrict__ g1) {
  int idx = blockIdx.x * 256 + threadIdx.x;
  int co = idx & 7, v = (idx >> 3) & (PR3 - 1), b = idx >> 18;
  const float invM = 1.0f / (8.0f * PR3);
  float s = st[(b * 8 + co) * 2], ssv = st[(b * 8 + co) * 2 + 1];
  float mu = s * invM, var = ssv * invM - mu * mu;
  float rstd = rsqrtf(var + 1e-5f);
  const float4* rp = (const float4*)(raw + ((size_t)(b * PR3 + v) * PC + co * 8));
  float4 A = rp[0], B4 = rp[1];
  float vals[8] = {A.x, A.y, A.z, A.w, B4.x, B4.y, B4.z, B4.w};
  unsigned short h[8];
  #pragma unroll
  for (int k = 0; k < 8; ++k) {
    int c = co * 8 + k;
    float y = (vals[k] - mu) * rstd * gw[c] + gb[c];
    float sw = y / (1.0f + expf(-y));
    h[k] = f2bf(sw);
  }
  int z = v >> 10, yy = (v >> 5) & 31, x = v & 31;
  size_t o = ((((size_t)b * PRP + (z + 1)) * PRP + (yy + 1)) * PRP + (x + 1)) * PC + co * 8;
  uint4 pk;
  pk.x = h[0] | ((unsigned)h[1] << 16); pk.y = h[2] | ((unsigned)h[3] << 16);
  pk.z = h[4] | ((unsigned)h[5] << 16); pk.w = h[6] | ((unsigned)h[7] << 16);
  *(uint4*)(g1 + o) = pk;
}

__global__ void gn_inplace_kernel(float* __restrict__ raw, const float* __restrict__ st,
                                  const float* __restrict__ gw, const float* __restrict__ gb) {
  int idx = blockIdx.x * 256 + threadIdx.x;
  int co = idx & 7, v = (idx >> 3) & (PR3 - 1), b = idx >> 18;
  const float invM = 1.0f / (8.0f * PR3);
  float s = st[(b * 8 + co) * 2], ssv = st[(b * 8 + co) * 2 + 1];
  float mu = s * invM, var = ssv * invM - mu * mu;
  float rstd = rsqrtf(var + 1e-5f);
  float4* rp = (float4*)(raw + ((size_t)(b * PR3 + v) * PC + co * 8));
  float4 A = rp[0], B4 = rp[1];
  float vals[8] = {A.x, A.y, A.z, A.w, B4.x, B4.y, B4.z, B4.w};
  #pragma unroll
  for (int k = 0; k < 8; ++k) {
    int c = co * 8 + k;
    vals[k] = (vals[k] - mu) * rstd * gw[c] + gb[c];
  }
  rp[0] = make_float4(vals[0], vals[1], vals[2], vals[3]);
  rp[1] = make_float4(vals[4], vals[5], vals[6], vals[7]);
}

// ---------------------------------------------------------------------------
// 8) point branch: p = W @ f + b (fp32), store raw (B,C,N), GN partials
// ---------------------------------------------------------------------------
__global__ void pf_kernel(const float* __restrict__ feats, const float* __restrict__ wt,
                          const float* __restrict__ pb, float* __restrict__ praw,
                          float* __restrict__ stats) {
  int b = blockIdx.y, n0 = blockIdx.x * 64, t = threadIdx.x;
  __shared__ float fl[64 * 65];
  __shared__ float wl[64 * 64];
  for (int k = 0; k < 16; ++k) {
    int i = t + k * 256;
    int c = i >> 6, p = i & 63;
    fl[c * 65 + p] = feats[((size_t)b * PC + c) * PN + n0 + p];
    wl[i] = wt[i];
  }
  __syncthreads();
  int n = t & 63, q = t >> 6;
  float acc[16];
  #pragma unroll
  for (int j = 0; j < 16; ++j) acc[j] = pb[q * 16 + j];
  for (int ci = 0; ci < 64; ++ci) {
    float v = fl[ci * 65 + n];
    #pragma unroll
    for (int j = 0; j < 16; ++j) acc[j] += v * wl[ci * 64 + q * 16 + j];
  }
  float s[2] = {0.f, 0.f}, ss[2] = {0.f, 0.f};
  #pragma unroll
  for (int j = 0; j < 16; ++j) {
    int o = q * 16 + j;
    praw[((size_t)b * PC + o) * PN + n0 + n] = acc[j];
    int h = j >> 3;
    s[h] += acc[j]; ss[h] += acc[j] * acc[j];
  }
  #pragma unroll
  for (int h = 0; h < 2; ++h) {
    for (int off = 32; off > 0; off >>= 1) {
      s[h] += __shfl_down(s[h], off);
      ss[h] += __shfl_down(ss[h], off);
    }
  }
  if (n == 0) {
    #pragma unroll
    for (int h = 0; h < 2; ++h) {
      atomicAdd(&stats[((size_t)b * 8 + 2 * q + h) * 2 + 0], s[h]);
      atomicAdd(&stats[((size_t)b * 8 + 2 * q + h) * 2 + 1], ss[h]);
    }
  }
}

// ---------------------------------------------------------------------------
// 9) trilinear devoxelize + point-branch GN+Swish + add -> out (B,C,N) fp32
// ---------------------------------------------------------------------------
__global__ void devox_kernel(const float* __restrict__ g2, const float* __restrict__ nc,
                             const float* __restrict__ praw, const float* __restrict__ stpf,
                             const float* __restrict__ pgw, const float* __restrict__ pgb,
                             float* __restrict__ out) {
  int b = blockIdx.y, n0 = blockIdx.x * 64, t = threadIdx.x;
  __shared__ float lt[64][65];
  int wv = t >> 6, c = t & 63;
  for (int i = 0; i < 16; ++i) {
    int p = wv * 16 + i, n = n0 + p;
    float fx = nc[((size_t)b * 3 + 0) * PN + n];
    float fy = nc[((size_t)b * 3 + 1) * PN + n];
    float fz = nc[((size_t)b * 3 + 2) * PN + n];
    float flx = floorf(fx), fly = floorf(fy), flz = floorf(fz);
    int x0 = (int)flx, y0 = (int)fly, z0 = (int)flz;
    int x1 = min(x0 + 1, 31), y1 = min(y0 + 1, 31), z1 = min(z0 + 1, 31);
    float wx1 = fx - flx, wy1 = fy - fly, wz1 = fz - flz;
    float wx0 = 1.f - wx1, wy0 = 1.f - wy1, wz0 = 1.f - wz1;
    const float* gb2 = g2 + (size_t)b * PR3 * PC + c;
    float a = 0.f;
    a += gb2[(size_t)((x0 * PR + y0) * PR + z0) * PC] * (wx0 * wy0 * wz0);
    a += gb2[(size_t)((x0 * PR + y0) * PR + z1) * PC] * (wx0 * wy0 * wz1);
    a += gb2[(size_t)((x0 * PR + y1) * PR + z0) * PC] * (wx0 * wy1 * wz0);
    a += gb2[(size_t)((x0 * PR + y1) * PR + z1) * PC] * (wx0 * wy1 * wz1);
    a += gb2[(size_t)((x1 * PR + y0) * PR + z0) * PC] * (wx1 * wy0 * wz0);
    a += gb2[(size_t)((x1 * PR + y0) * PR + z1) * PC] * (wx1 * wy0 * wz1);
    a += gb2[(size_t)((x1 * PR + y1) * PR + z0) * PC] * (wx1 * wy1 * wz0);
    a += gb2[(size_t)((x1 * PR + y1) * PR + z1) * PC] * (wx1 * wy1 * wz1);
    lt[p][c] = a;
  }
  __syncthreads();
  int n = t & 63, q = t >> 6;
  const float invM = 1.0f / (8.0f * PN);
  float mu[2], rs[2];
  #pragma unroll
  for (int h = 0; h < 2; ++h) {
    float s = stpf[((size_t)b * 8 + 2 * q + h) * 2];
    float ssv = stpf[((size_t)b * 8 + 2 * q + h) * 2 + 1];
    float m_ = s * invM;
    mu[h] = m_;
    rs[h] = rsqrtf(ssv * invM - m_ * m_ + 1e-5f);
  }
  #pragma unroll
  for (int j = 0; j < 16; ++j) {
    int cc = q * 16 + j, h = j >> 3;
    float p_ = praw[((size_t)b * PC + cc) * PN + n0 + n];
    float y = (p_ - mu[h]) * rs[h] * pgw[cc] + pgb[cc];
    float sw = y / (1.0f + expf(-y));
    out[((size_t)b * PC + cc) * PN + n0 + n] = lt[n][cc] + sw;
  }
}

// ---------------------------------------------------------------------------
extern "C" void kernel_launch(void* const* d_in, const int* in_sizes, int n_in,
                              void* d_out, int out_size, void* d_ws, size_t ws_size,
                              hipStream_t stream) {
  (void)in_sizes; (void)n_in; (void)out_size; (void)ws_size;
  const float* features = (const float*)d_in[0];
  const float* coords   = (const float*)d_in[1];
  const float* conv1_w  = (const float*)d_in[2];
  const float* conv1_b  = (const float*)d_in[3];
  const float* gn1_w    = (const float*)d_in[4];
  const float* gn1_b    = (const float*)d_in[5];
  const float* conv2_w  = (const float*)d_in[6];
  const float* conv2_b  = (const float*)d_in[7];
  const float* gn2_w    = (const float*)d_in[8];
  const float* gn2_b    = (const float*)d_in[9];
  const float* pf_w     = (const float*)d_in[10];
  const float* pf_b     = (const float*)d_in[11];
  const float* pf_gn_w  = (const float*)d_in[12];
  const float* pf_gn_b  = (const float*)d_in[13];
  float* out = (float*)d_out;

  char* ws = (char*)d_ws;
  size_t off = 0;
  auto alloc = [&](size_t bytes) { size_t r = (off + 255) & ~(size_t)255; off = r + bytes; return r; };

  const size_t sz_nc   = (size_t)PB * 3 * PN * 4;
  const size_t sz_ms   = 256;
  const size_t sz_vf   = (size_t)PB * PN * 4;
  const size_t sz_cnt  = (size_t)PB * PR3 * 4;
  const size_t sz_st   = (size_t)PB * 8 * 2 * 4;
  const size_t sz_raw  = (size_t)PB * PR3 * PC * 4;            // 67 MB (sums / conv raw)
  const size_t sz_gpad = (size_t)PB * PRP * PRP * PRP * PC * 2; // 40 MB bf16 padded
  const size_t sz_wkt  = (size_t)27 * 64 * 64 * 2;
  const size_t sz_pfw  = (size_t)64 * 64 * 4;

  float*          nc    = (float*)(ws + alloc(sz_nc));
  float*          ms    = (float*)(ws + alloc(sz_ms));
  int*            vflat = (int*)(ws + alloc(sz_vf));
  float*          cnts  = (float*)(ws + alloc(sz_cnt));
  float*          st1   = (float*)(ws + alloc(sz_st));
  float*          st2   = (float*)(ws + alloc(sz_st));
  float*          stpf  = (float*)(ws + alloc(sz_st));
  float*          graw  = (float*)(ws + alloc(sz_raw));   // sums -> conv1 raw -> conv2 raw -> g2
  unsigned short* g0    = (unsigned short*)(ws + alloc(sz_gpad));
  unsigned short* g1    = (unsigned short*)(ws + alloc(sz_gpad));
  unsigned short* wkt1  = (unsigned short*)(ws + alloc(sz_wkt));
  unsigned short* wkt2  = (unsigned short*)(ws + alloc(sz_wkt));
  float*          pfwt  = (float*)(ws + alloc(sz_pfw));
  float*          praw  = (float*)g0;  // overlay: g0 dead after conv1 reads it

  hipMemsetAsync(cnts, 0, sz_cnt, stream);
  hipMemsetAsync(graw, 0, sz_raw, stream);
  hipMemsetAsync(g0, 0, sz_gpad, stream);
  hipMemsetAsync(g1, 0, sz_gpad, stream);
  hipMemsetAsync(st1, 0, sz_st, stream);
  hipMemsetAsync(st2, 0, sz_st, stream);
  hipMemsetAsync(stpf, 0, sz_st, stream);

  tconv_kernel<<<(27 * 4096 + 255) / 256, 256, 0, stream>>>(conv1_w, wkt1);
  tconv_kernel<<<(27 * 4096 + 255) / 256, 256, 0, stream>>>(conv2_w, wkt2);
  tpf_kernel<<<16, 256, 0, stream>>>(pf_w, pfwt);

  coord_stats_kernel<<<PB, 256, 0, stream>>>(coords, ms);
  nc_vox_kernel<<<(PB * PN) / 256, 256, 0, stream>>>(coords, ms, nc, vflat);
  scatter_kernel<<<dim3(PN / 64, PB), 256, 0, stream>>>(features, vflat, graw, cnts);
  finalize_kernel<<<(PB * PR3 * 8) / 256, 256, 0, stream>>>(graw, cnts, g0);

  const size_t conv_lds = 128000 + 2 * 8192;
  conv3_kernel<<<dim3(64, PB), 256, conv_lds, stream>>>(g0, wkt1, conv1_b, graw, st1);
  gn_swish_bf16_kernel<<<(PB * PR3 * 8) / 256, 256, 0, stream>>>(graw, st1, gn1_w, gn1_b, g1);

  pf_kernel<<<dim3(PN / 64, PB), 256, 0, stream>>>(features, pfwt, pf_b, praw, stpf);

  conv3_kernel<<<dim3(64, PB), 256, conv_lds, stream>>>(g1, wkt2, conv2_b, graw, st2);
  gn_inplace_kernel<<<(PB * PR3 * 8) / 256, 256, 0, stream>>>(graw, st2, gn2_w, gn2_b);

  devox_kernel<<<dim3(PN / 64, PB), 256, 0, stream>>>(graw, nc, praw, stpf, pf_gn_w, pf_gn_b, out);
}

// Round 6
// 615.615 us; speedup vs baseline: 1.1591x; 1.1591x over previous
//
#include <hip/hip_runtime.h>
#include <hip/hip_bf16.h>
#include <stdint.h>

// Problem constants (fixed by reference setup_inputs)
#define PB 8          // batch
#define PN 16384      // points
#define PC 64         // channels (Cin == Cout == 64)
#define PR 32         // voxel resolution
#define PR3 32768     // R^3
#define PRP 34        // padded resolution
#define PRP3 (PRP * PRP * PRP)

typedef __attribute__((ext_vector_type(8))) short bf16x8;
typedef __attribute__((ext_vector_type(16))) float f32x16;

__device__ __forceinline__ unsigned short f2bf(float f) {
  union { float f; unsigned u; } v; v.f = f;
  unsigned r = v.u + 0x7FFFu + ((v.u >> 16) & 1u);
  return (unsigned short)(r >> 16);
}

// ---------------------------------------------------------------------------
// 0) zero the 1-voxel pad shell of a padded bf16 grid (interior is fully
//    overwritten by finalize/gn_swish, so no full memset needed)
// ---------------------------------------------------------------------------
__global__ void zero_pad_kernel(unsigned short* __restrict__ g) {
  int idx = blockIdx.x * 256 + threadIdx.x;   // chunk index: (((b*34+z)*34+y)*34+x)*8+co
  if (idx >= PB * PRP3 * 8) return;
  int v = (idx >> 3) % PRP3;
  int z = v / (PRP * PRP), rem = v % (PRP * PRP), y = rem / PRP, x = rem % PRP;
  bool border = (z == 0) | (z == PRP - 1) | (y == 0) | (y == PRP - 1) | (x == 0) | (x == PRP - 1);
  if (!border) return;
  *(uint4*)(g + ((size_t)idx << 3)) = make_uint4(0, 0, 0, 0);
}

// ---------------------------------------------------------------------------
// 1) per-batch coord stats: mean(3) and scale = 2*max||c-mean||
// ---------------------------------------------------------------------------
__global__ void coord_stats_kernel(const float* __restrict__ coords, float* __restrict__ ms) {
  int b = blockIdx.x, t = threadIdx.x;
  __shared__ float wsum[4][3];
  __shared__ float wmax[4];
  __shared__ float meanv[3];
  const float* c0 = coords + (size_t)b * 3 * PN;
  float s0 = 0.f, s1 = 0.f, s2 = 0.f;
  for (int n = t; n < PN; n += 256) {
    s0 += c0[n]; s1 += c0[PN + n]; s2 += c0[2 * PN + n];
  }
  for (int off = 32; off > 0; off >>= 1) {
    s0 += __shfl_down(s0, off); s1 += __shfl_down(s1, off); s2 += __shfl_down(s2, off);
  }
  if ((t & 63) == 0) { wsum[t >> 6][0] = s0; wsum[t >> 6][1] = s1; wsum[t >> 6][2] = s2; }
  __syncthreads();
  if (t == 0) {
    for (int d = 0; d < 3; ++d)
      meanv[d] = (wsum[0][d] + wsum[1][d] + wsum[2][d] + wsum[3][d]) * (1.0f / PN);
  }
  __syncthreads();
  float m0 = meanv[0], m1 = meanv[1], m2 = meanv[2];
  float mx = 0.f;
  for (int n = t; n < PN; n += 256) {
    float dx = c0[n] - m0, dy = c0[PN + n] - m1, dz = c0[2 * PN + n] - m2;
    mx = fmaxf(mx, dx * dx + dy * dy + dz * dz);
  }
  for (int off = 32; off > 0; off >>= 1) mx = fmaxf(mx, __shfl_down(mx, off));
  if ((t & 63) == 0) wmax[t >> 6] = mx;
  __syncthreads();
  if (t == 0) {
    float m = fmaxf(fmaxf(wmax[0], wmax[1]), fmaxf(wmax[2], wmax[3]));
    ms[b * 4 + 0] = meanv[0]; ms[b * 4 + 1] = meanv[1]; ms[b * 4 + 2] = meanv[2];
    ms[b * 4 + 3] = 2.0f * sqrtf(m);
  }
}

// ---------------------------------------------------------------------------
// 2) normalized coords + rounded flat voxel index
// ---------------------------------------------------------------------------
__global__ void nc_vox_kernel(const float* __restrict__ coords, const float* __restrict__ ms,
                              float* __restrict__ nc, int* __restrict__ vflat) {
  int i = blockIdx.x * 256 + threadIdx.x;
  if (i >= PB * PN) return;
  int b = i >> 14, n = i & (PN - 1);
  float sc = ms[b * 4 + 3];
  int vi[3];
  #pragma unroll
  for (int d = 0; d < 3; ++d) {
    float c = coords[((size_t)b * 3 + d) * PN + n];
    float q = (c - ms[b * 4 + d]) / sc + 0.5f;
    float v = fminf(fmaxf(q * 32.0f, 0.0f), 31.0f);
    nc[((size_t)b * 3 + d) * PN + n] = v;
    vi[d] = (int)rintf(v);  // round half to even, matches jnp.round
  }
  vflat[i] = (vi[0] * PR + vi[1]) * PR + vi[2];
}

// ---------------------------------------------------------------------------
// 3) scatter-add features into (B, R3, C) sums + counts. LDS transpose so the
//    64 atomic lanes cover 64 consecutive channels (256B bursts).
// ---------------------------------------------------------------------------
__global__ void scatter_kernel(const float* __restrict__ feats, const int* __restrict__ vflat,
                               float* __restrict__ sums, float* __restrict__ cnts) {
  int b = blockIdx.y, p0 = blockIdx.x * 64, t = threadIdx.x;
  __shared__ float fl[64 * 65];
  for (int k = 0; k < 16; ++k) {
    int i = t + k * 256;
    int c = i >> 6, p = i & 63;
    fl[c * 65 + p] = feats[((size_t)b * PC + c) * PN + p0 + p];
  }
  __syncthreads();
  if (t < 64) atomicAdd(&cnts[b * PR3 + vflat[b * PN + p0 + t]], 1.0f);
  int cc = t & 63, pp = t >> 6;
  for (int i = 0; i < 16; ++i) {
    int p = pp * 16 + i;
    int v = vflat[b * PN + p0 + p];
    atomicAdd(&sums[((size_t)b * PR3 + v) * PC + cc], fl[cc * 65 + p]);
  }
}

// ---------------------------------------------------------------------------
// 4) finalize: avg = sums/max(cnt,1) -> bf16 into padded grid (B,34,34,34,64)
// ---------------------------------------------------------------------------
__global__ void finalize_kernel(const float* __restrict__ sums, const float* __restrict__ cnts,
                                unsigned short* __restrict__ g0) {
  int idx = blockIdx.x * 256 + threadIdx.x;   // over B*R3*8 chunks
  int co = idx & 7, v = (idx >> 3) & (PR3 - 1), b = idx >> 18;
  float cnt = cnts[b * PR3 + v];
  float inv = 1.0f / fmaxf(cnt, 1.0f);
  const float4* sp = (const float4*)(sums + ((size_t)(b * PR3 + v) * PC) + co * 8);
  float4 A = sp[0], B4 = sp[1];
  float vals[8] = {A.x, A.y, A.z, A.w, B4.x, B4.y, B4.z, B4.w};
  unsigned short h[8];
  #pragma unroll
  for (int k = 0; k < 8; ++k) h[k] = f2bf(vals[k] * inv);
  int z = v >> 10, y = (v >> 5) & 31, x = v & 31;
  size_t o = ((((size_t)b * PRP + (z + 1)) * PRP + (y + 1)) * PRP + (x + 1)) * PC + co * 8;
  uint4 pk;
  pk.x = h[0] | ((unsigned)h[1] << 16); pk.y = h[2] | ((unsigned)h[3] << 16);
  pk.z = h[4] | ((unsigned)h[5] << 16); pk.w = h[6] | ((unsigned)h[7] << 16);
  *(uint4*)(g0 + o) = pk;
}

// ---------------------------------------------------------------------------
// 5) weight transposes: conv w(O,I,3,3,3) -> bf16 [tap][o][i]; pf w(O,I) -> [i][o]
// ---------------------------------------------------------------------------
__global__ void tconv_kernel(const float* __restrict__ w, unsigned short* __restrict__ wkt) {
  int idx = blockIdx.x * 256 + threadIdx.x;
  if (idx >= 27 * 64 * 64) return;
  int i = idx & 63, o = (idx >> 6) & 63, tap = idx >> 12;
  wkt[idx] = f2bf(w[(o * 64 + i) * 27 + tap]);
}
__global__ void tpf_kernel(const float* __restrict__ pw, float* __restrict__ wt) {
  int idx = blockIdx.x * 256 + threadIdx.x;
  if (idx >= 4096) return;
  int o = idx & 63, ci = idx >> 6;
  wt[ci * 64 + o] = pw[o * 64 + ci];
}

// ---------------------------------------------------------------------------
// 6) 3x3x3 conv, 64->64 ch, bf16 MFMA 32x32x16 implicit GEMM.
// ---------------------------------------------------------------------------
__global__ __launch_bounds__(256, 1) void conv3_kernel(
    const unsigned short* __restrict__ gin, const unsigned short* __restrict__ wkt,
    const float* __restrict__ bias, float* __restrict__ outp, float* __restrict__ stats) {
  extern __shared__ char smem[];  // [0,128000) input, [128000,144384) weights dbuf
  const int t = threadIdx.x;
  const int tile = blockIdx.x, b = blockIdx.y;
  const int tz = tile >> 4, ty = (tile >> 2) & 3, tx = tile & 3;
  const int z0 = tz * 8, y0 = ty * 8, x0 = tx * 8;

  // stage input tile (1000 voxels x 128B = 8000 16B chunks)
  {
    const size_t gbase = (size_t)b * (PRP * PRP * PRP * PC);
    for (int it = 0; it < 32; ++it) {
      int q = t + it * 256;
      if (q < 8000) {
        int vl = q >> 3, cc = q & 7;
        int zz = vl / 100, rem = vl - zz * 100;
        int yy = rem / 10, xx = rem - yy * 10;
        size_t go = gbase + (((size_t)(z0 + zz) * PRP + (y0 + yy)) * PRP + (x0 + xx)) * PC + cc * 8;
        uint4 d = *(const uint4*)(gin + go);
        *(uint4*)(smem + (vl * 128 + ((cc ^ (vl & 7)) << 4))) = d;
      }
    }
  }
  // stage weights for tap 0 into buffer 0
  {
    #pragma unroll
    for (int u = 0; u < 2; ++u) {
      int q = t * 2 + u;
      int o = q >> 3, cc = q & 7;
      uint4 d = ((const uint4*)wkt)[q];
      *(uint4*)(smem + 128000 + (o * 128 + ((cc ^ (o & 7)) << 4))) = d;
    }
  }
  __syncthreads();

  const int wv = t >> 6, l31 = t & 31, hi = (t >> 5) & 1;
  int vbase[4];
  #pragma unroll
  for (int m = 0; m < 4; ++m) {
    int vi = wv * 128 + m * 32 + l31;
    int z = vi >> 6, y = (vi >> 3) & 7, x = vi & 7;
    vbase[m] = z * 100 + y * 10 + x;
  }

  f32x16 acc[4][2];
  #pragma unroll
  for (int m = 0; m < 4; ++m)
    #pragma unroll
    for (int nb = 0; nb < 2; ++nb)
      #pragma unroll
      for (int r = 0; r < 16; ++r) acc[m][nb][r] = 0.0f;

  for (int tap = 0; tap < 27; ++tap) {
    if (tap + 1 < 27) {  // prefetch next tap's weights into other buffer
      char* wb = smem + 128000 + (((tap + 1) & 1) * 8192);
      #pragma unroll
      for (int u = 0; u < 2; ++u) {
        int q = t * 2 + u;
        int o = q >> 3, cc = q & 7;
        uint4 d = ((const uint4*)wkt)[(tap + 1) * 512 + q];
        *(uint4*)(wb + (o * 128 + ((cc ^ (o & 7)) << 4))) = d;
      }
    }
    const char* wb = smem + 128000 + ((tap & 1) * 8192);
    int dz = tap / 9, r9 = tap - dz * 9;
    int dy = r9 / 3, dx = r9 - dy * 3;
    int toff = dz * 100 + dy * 10 + dx;
    #pragma unroll
    for (int kk = 0; kk < 4; ++kk) {
      bf16x8 afr[4], bfr[2];
      #pragma unroll
      for (int m = 0; m < 4; ++m) {
        int vl = vbase[m] + toff;
        afr[m] = *(const bf16x8*)(smem + (vl * 128 + (((kk * 2 + hi) ^ (vl & 7)) << 4)));
      }
      #pragma unroll
      for (int nb = 0; nb < 2; ++nb) {
        int o = nb * 32 + l31;
        bfr[nb] = *(const bf16x8*)(wb + (o * 128 + (((kk * 2 + hi) ^ (o & 7)) << 4)));
      }
      #pragma unroll
      for (int m = 0; m < 4; ++m)
        #pragma unroll
        for (int nb = 0; nb < 2; ++nb)
          acc[m][nb] = __builtin_amdgcn_mfma_f32_32x32x16_bf16(afr[m], bfr[nb], acc[m][nb], 0, 0, 0);
    }
    __syncthreads();
  }

  // epilogue: +bias, store raw fp32 (B,R3,C), accumulate GN partials
  float sg[2] = {0.f, 0.f}, ssg[2] = {0.f, 0.f};
  #pragma unroll
  for (int nb = 0; nb < 2; ++nb) {
    int cn = nb * 32 + l31;
    float bv = bias[cn];
    #pragma unroll
    for (int m = 0; m < 4; ++m) {
      #pragma unroll
      for (int r = 0; r < 16; ++r) {
        int row = (r & 3) + 8 * (r >> 2) + 4 * hi;
        int vi = wv * 128 + m * 32 + row;
        int Z = z0 + (vi >> 6), Y = y0 + ((vi >> 3) & 7), X = x0 + (vi & 7);
        int vg = (Z * PR + Y) * PR + X;
        float val = acc[m][nb][r] + bv;
        outp[((size_t)b * PR3 + vg) * PC + cn] = val;
        sg[nb] += val; ssg[nb] += val * val;
      }
    }
  }
  #pragma unroll
  for (int nb = 0; nb < 2; ++nb) {
    sg[nb] += __shfl_down(sg[nb], 32);
    ssg[nb] += __shfl_down(ssg[nb], 32);
    #pragma unroll
    for (int off = 1; off <= 4; off <<= 1) {
      sg[nb] += __shfl_xor(sg[nb], off);
      ssg[nb] += __shfl_xor(ssg[nb], off);
    }
  }
  if (hi == 0 && (l31 & 7) == 0) {
    #pragma unroll
    for (int nb = 0; nb < 2; ++nb) {
      int g = (nb * 32 + l31) >> 3;
      atomicAdd(&stats[((size_t)b * 8 + g) * 2 + 0], sg[nb]);
      atomicAdd(&stats[((size_t)b * 8 + g) * 2 + 1], ssg[nb]);
    }
  }
}

// ---------------------------------------------------------------------------
// 7) GN (+Swish) from raw fp32 -> bf16 padded grid      (after conv1)
// ---------------------------------------------------------------------------
__global__ void gn_swish_bf16_kernel(const float* __restrict__ raw, const float* __restrict__ st,
                                     const float* __restrict__ gw, const float* __restrict__ gb,
                                     unsigned short* __restrict__ g1) {
  int idx = blockIdx.x * 256 + threadIdx.x;
  int co = idx & 7, v = (idx >> 3) & (PR3 - 1), b = idx >> 18;
  const float invM = 1.0f / (8.0f * PR3);
  float s = st[(b * 8 + co) * 2], ssv = st[(b * 8 + co) * 2 + 1];
  float mu = s * invM, var = ssv * invM - mu * mu;
  float rstd = rsqrtf(var + 1e-5f);
  const float4* rp = (const float4*)(raw + ((size_t)(b * PR3 + v) * PC + co * 8));
  float4 A = rp[0], B4 = rp[1];
  float vals[8] = {A.x, A.y, A.z, A.w, B4.x, B4.y, B4.z, B4.w};
  unsigned short h[8];
  #pragma unroll
  for (int k = 0; k < 8; ++k) {
    int c = co * 8 + k;
    float y = (vals[k] - mu) * rstd * gw[c] + gb[c];
    float sw = y / (1.0f + expf(-y));
    h[k] = f2bf(sw);
  }
  int z = v >> 10, yy = (v >> 5) & 31, x = v & 31;
  size_t o = ((((size_t)b * PRP + (z + 1)) * PRP + (yy + 1)) * PRP + (x + 1)) * PC + co * 8;
  uint4 pk;
  pk.x = h[0] | ((unsigned)h[1] << 16); pk.y = h[2] | ((unsigned)h[3] << 16);
  pk.z = h[4] | ((unsigned)h[5] << 16); pk.w = h[6] | ((unsigned)h[7] << 16);
  *(uint4*)(g1 + o) = pk;
}

// ---------------------------------------------------------------------------
// 8) point branch: p = W @ f + b (fp32), 4x4 register tile per thread.
// ---------------------------------------------------------------------------
__global__ void pf_kernel(const float* __restrict__ feats, const float* __restrict__ wt,
                          const float* __restrict__ pb, float* __restrict__ praw,
                          float* __restrict__ stats) {
  int b = blockIdx.y, n0 = blockIdx.x * 64, t = threadIdx.x;
  __shared__ float fl[64 * 68];   // [ci][p], pad 68 for b128 alignment
  __shared__ float wl[64 * 64];   // [ci][o]
  for (int k = 0; k < 16; ++k) {
    int i = t + k * 256;
    int c = i >> 6, p = i & 63;
    fl[c * 68 + p] = feats[((size_t)b * PC + c) * PN + n0 + p];
    wl[i] = wt[i];
  }
  __syncthreads();
  int po = (t & 15) * 4;    // 4 points
  int oo = (t >> 4) * 4;    // 4 couts
  float acc[4][4];          // [point][cout]
  #pragma unroll
  for (int pi = 0; pi < 4; ++pi)
    #pragma unroll
    for (int oi = 0; oi < 4; ++oi) acc[pi][oi] = pb[oo + oi];
  for (int ci = 0; ci < 64; ++ci) {
    float4 fv = *(const float4*)(fl + ci * 68 + po);
    float4 wv = *(const float4*)(wl + ci * 64 + oo);
    float fa[4] = {fv.x, fv.y, fv.z, fv.w};
    float wa[4] = {wv.x, wv.y, wv.z, wv.w};
    #pragma unroll
    for (int pi = 0; pi < 4; ++pi)
      #pragma unroll
      for (int oi = 0; oi < 4; ++oi) acc[pi][oi] += fa[pi] * wa[oi];
  }
  // store: one float4 (4 points) per cout row
  #pragma unroll
  for (int oi = 0; oi < 4; ++oi) {
    float4 st4 = make_float4(acc[0][oi], acc[1][oi], acc[2][oi], acc[3][oi]);
    *(float4*)(praw + ((size_t)b * PC + oo + oi) * PN + n0 + po) = st4;
  }
  // GN partials: this thread's 16 values all belong to group oo>>3
  float s = 0.f, ss = 0.f;
  #pragma unroll
  for (int pi = 0; pi < 4; ++pi)
    #pragma unroll
    for (int oi = 0; oi < 4; ++oi) { float v = acc[pi][oi]; s += v; ss += v * v; }
  // within a wave: lanes 0-31 share one (wave,group), lanes 32-63 the other
  #pragma unroll
  for (int off = 1; off <= 16; off <<= 1) {
    s += __shfl_xor(s, off); ss += __shfl_xor(ss, off);
  }
  if ((t & 31) == 0) {
    int g = oo >> 3;
    atomicAdd(&stats[((size_t)b * 8 + g) * 2 + 0], s);
    atomicAdd(&stats[((size_t)b * 8 + g) * 2 + 1], ss);
  }
}

// ---------------------------------------------------------------------------
// 9) trilinear devoxelize (with fused GN2 affine: GN commutes with the gather
//    since trilinear weights sum to 1) + point-branch GN+Swish + add -> out
// ---------------------------------------------------------------------------
__global__ void devox_kernel(const float* __restrict__ g2raw, const float* __restrict__ nc,
                             const float* __restrict__ st2, const float* __restrict__ g2w,
                             const float* __restrict__ g2b,
                             const float* __restrict__ praw, const float* __restrict__ stpf,
                             const float* __restrict__ pgw, const float* __restrict__ pgb,
                             float* __restrict__ out) {
  int b = blockIdx.y, n0 = blockIdx.x * 64, t = threadIdx.x;
  __shared__ float lt[64][65];
  int wv = t >> 6, c = t & 63;
  // GN2 affine for channel c: y = a*sc + tc
  const float invV = 1.0f / (8.0f * PR3);
  float s2 = st2[(b * 8 + (c >> 3)) * 2], ss2 = st2[(b * 8 + (c >> 3)) * 2 + 1];
  float mu2 = s2 * invV;
  float rstd2 = rsqrtf(ss2 * invV - mu2 * mu2 + 1e-5f);
  float sc = rstd2 * g2w[c];
  float tc = g2b[c] - mu2 * sc;
  for (int i = 0; i < 16; ++i) {
    int p = wv * 16 + i, n = n0 + p;
    float fx = nc[((size_t)b * 3 + 0) * PN + n];
    float fy = nc[((size_t)b * 3 + 1) * PN + n];
    float fz = nc[((size_t)b * 3 + 2) * PN + n];
    float flx = floorf(fx), fly = floorf(fy), flz = floorf(fz);
    int x0 = (int)flx, y0 = (int)fly, z0 = (int)flz;
    int x1 = min(x0 + 1, 31), y1 = min(y0 + 1, 31), z1 = min(z0 + 1, 31);
    float wx1 = fx - flx, wy1 = fy - fly, wz1 = fz - flz;
    float wx0 = 1.f - wx1, wy0 = 1.f - wy1, wz0 = 1.f - wz1;
    const float* gb2 = g2raw + (size_t)b * PR3 * PC + c;
    float a = 0.f;
    a += gb2[(size_t)((x0 * PR + y0) * PR + z0) * PC] * (wx0 * wy0 * wz0);
    a += gb2[(size_t)((x0 * PR + y0) * PR + z1) * PC] * (wx0 * wy0 * wz1);
    a += gb2[(size_t)((x0 * PR + y1) * PR + z0) * PC] * (wx0 * wy1 * wz0);
    a += gb2[(size_t)((x0 * PR + y1) * PR + z1) * PC] * (wx0 * wy1 * wz1);
    a += gb2[(size_t)((x1 * PR + y0) * PR + z0) * PC] * (wx1 * wy0 * wz0);
    a += gb2[(size_t)((x1 * PR + y0) * PR + z1) * PC] * (wx1 * wy0 * wz1);
    a += gb2[(size_t)((x1 * PR + y1) * PR + z0) * PC] * (wx1 * wy1 * wz0);
    a += gb2[(size_t)((x1 * PR + y1) * PR + z1) * PC] * (wx1 * wy1 * wz1);
    lt[p][c] = a * sc + tc;
  }
  __syncthreads();
  int n = t & 63, q = t >> 6;
  const float invM = 1.0f / (8.0f * PN);
  float mu[2], rs[2];
  #pragma unroll
  for (int h = 0; h < 2; ++h) {
    float s = stpf[((size_t)b * 8 + 2 * q + h) * 2];
    float ssv = stpf[((size_t)b * 8 + 2 * q + h) * 2 + 1];
    float m_ = s * invM;
    mu[h] = m_;
    rs[h] = rsqrtf(ssv * invM - m_ * m_ + 1e-5f);
  }
  #pragma unroll
  for (int j = 0; j < 16; ++j) {
    int cc = q * 16 + j, h = j >> 3;
    float p_ = praw[((size_t)b * PC + cc) * PN + n0 + n];
    float y = (p_ - mu[h]) * rs[h] * pgw[cc] + pgb[cc];
    float sw = y / (1.0f + expf(-y));
    out[((size_t)b * PC + cc) * PN + n0 + n] = lt[n][cc] + sw;
  }
}

// ---------------------------------------------------------------------------
extern "C" void kernel_launch(void* const* d_in, const int* in_sizes, int n_in,
                              void* d_out, int out_size, void* d_ws, size_t ws_size,
                              hipStream_t stream) {
  (void)in_sizes; (void)n_in; (void)out_size; (void)ws_size;
  const float* features = (const float*)d_in[0];
  const float* coords   = (const float*)d_in[1];
  const float* conv1_w  = (const float*)d_in[2];
  const float* conv1_b  = (const float*)d_in[3];
  const float* gn1_w    = (const float*)d_in[4];
  const float* gn1_b    = (const float*)d_in[5];
  const float* conv2_w  = (const float*)d_in[6];
  const float* conv2_b  = (const float*)d_in[7];
  const float* gn2_w    = (const float*)d_in[8];
  const float* gn2_b    = (const float*)d_in[9];
  const float* pf_w     = (const float*)d_in[10];
  const float* pf_b     = (const float*)d_in[11];
  const float* pf_gn_w  = (const float*)d_in[12];
  const float* pf_gn_b  = (const float*)d_in[13];
  float* out = (float*)d_out;

  char* ws = (char*)d_ws;
  size_t off = 0;
  auto alloc = [&](size_t bytes) { size_t r = (off + 255) & ~(size_t)255; off = r + bytes; return r; };

  const size_t sz_nc   = (size_t)PB * 3 * PN * 4;
  const size_t sz_ms   = 256;
  const size_t sz_vf   = (size_t)PB * PN * 4;
  const size_t sz_cnt  = (size_t)PB * PR3 * 4;
  const size_t sz_st   = (size_t)PB * 8 * 2 * 4;
  const size_t sz_raw  = (size_t)PB * PR3 * PC * 4;            // 67 MB (sums / conv raw)
  const size_t sz_gpad = (size_t)PB * PRP3 * PC * 2;           // 40 MB bf16 padded
  const size_t sz_wkt  = (size_t)27 * 64 * 64 * 2;
  const size_t sz_pfw  = (size_t)64 * 64 * 4;

  float*          nc    = (float*)(ws + alloc(sz_nc));
  float*          ms    = (float*)(ws + alloc(sz_ms));
  int*            vflat = (int*)(ws + alloc(sz_vf));
  float*          cnts  = (float*)(ws + alloc(sz_cnt));
  float*          st1   = (float*)(ws + alloc(sz_st));
  float*          st2   = (float*)(ws + alloc(sz_st));
  float*          stpf  = (float*)(ws + alloc(sz_st));
  float*          graw  = (float*)(ws + alloc(sz_raw));   // sums -> conv1 raw -> conv2 raw
  unsigned short* g0    = (unsigned short*)(ws + alloc(sz_gpad));
  unsigned short* g1    = (unsigned short*)(ws + alloc(sz_gpad));
  unsigned short* wkt1  = (unsigned short*)(ws + alloc(sz_wkt));
  unsigned short* wkt2  = (unsigned short*)(ws + alloc(sz_wkt));
  float*          pfwt  = (float*)(ws + alloc(sz_pfw));
  float*          praw  = (float*)g0;  // overlay: g0 dead after conv1 reads it

  hipMemsetAsync(cnts, 0, sz_cnt, stream);
  hipMemsetAsync(graw, 0, sz_raw, stream);
  hipMemsetAsync(st1, 0, sz_st, stream);
  hipMemsetAsync(st2, 0, sz_st, stream);
  hipMemsetAsync(stpf, 0, sz_st, stream);

  // pad shells (interior fully overwritten by finalize / gn_swish)
  const int zp_blocks = (PB * PRP3 * 8 + 255) / 256;
  zero_pad_kernel<<<zp_blocks, 256, 0, stream>>>(g0);
  zero_pad_kernel<<<zp_blocks, 256, 0, stream>>>(g1);

  tconv_kernel<<<(27 * 4096 + 255) / 256, 256, 0, stream>>>(conv1_w, wkt1);
  tconv_kernel<<<(27 * 4096 + 255) / 256, 256, 0, stream>>>(conv2_w, wkt2);
  tpf_kernel<<<16, 256, 0, stream>>>(pf_w, pfwt);

  coord_stats_kernel<<<PB, 256, 0, stream>>>(coords, ms);
  nc_vox_kernel<<<(PB * PN) / 256, 256, 0, stream>>>(coords, ms, nc, vflat);
  scatter_kernel<<<dim3(PN / 64, PB), 256, 0, stream>>>(features, vflat, graw, cnts);
  finalize_kernel<<<(PB * PR3 * 8) / 256, 256, 0, stream>>>(graw, cnts, g0);

  const size_t conv_lds = 128000 + 2 * 8192;
  conv3_kernel<<<dim3(64, PB), 256, conv_lds, stream>>>(g0, wkt1, conv1_b, graw, st1);
  gn_swish_bf16_kernel<<<(PB * PR3 * 8) / 256, 256, 0, stream>>>(graw, st1, gn1_w, gn1_b, g1);

  pf_kernel<<<dim3(PN / 64, PB), 256, 0, stream>>>(features, pfwt, pf_b, praw, stpf);

  conv3_kernel<<<dim3(64, PB), 256, conv_lds, stream>>>(g1, wkt2, conv2_b, graw, st2);

  devox_kernel<<<dim3(PN / 64, PB), 256, 0, stream>>>(graw, nc, st2, gn2_w, gn2_b,
                                                      praw, stpf, pf_gn_w, pf_gn_b, out);
}